// Round 9
// baseline (225.269 us; speedup 1.0000x reference)
//
#include <hip/hip_runtime.h>
#include <math.h>

// Problem constants
#define BATCH 8
#define NN 64
#define DD 65536            // 64*32*32 feature length (contiguous per [b,n])
#define BPB 64              // blocks per batch -> grid = 512
#define NBLK (BATCH * BPB)
#define KC (DD / BPB)       // 1024 K per block
#define CHUNK 128           // K per staged LDS chunk
#define NCHUNK (KC / CHUNK) // 8
#define LROW 144            // LDS row stride in bf16 (128 + 16 pad)
#define NTRI 10             // upper-triangle 16x16 tiles of the 64x64 Gram
#define PSZ (NTRI * 256)    // floats per partial (2560)

typedef float  floatx4 __attribute__((ext_vector_type(4)));
typedef __bf16 bf16x8  __attribute__((ext_vector_type(8)));

// ---------------------------------------------------------------------------
// Stage 1: R9 — COALESCED loads. Previous rounds' vmem pattern scattered 16
// 128-B segments (rows 256 KB apart) per instruction: fine when L2-served
// (R4: 6.4 TB/s) but 0.9-1.8 TB/s from cold HBM (R5-R8), vs 6.9 TB/s for the
// contiguous fill kernel. Now: block-cooperatively stage 64 rows x 128 K per
// chunk; each load instruction covers 2 contiguous 512-B segments. Convert
// fp32->bf16 in-register, write wave-conflict-free to LDS, single barrier
// per chunk (dbuf). Waves split K WITHIN the chunk (wave w = K-step w), so
// every input byte is still loaded exactly once. Tri-tile accumulators and
// cross-wave end-reduce as in R6.
// ---------------------------------------------------------------------------
__global__ __launch_bounds__(256, 3) void gram_partial_kernel(const float* __restrict__ a,
                                                              float* __restrict__ part) {
    __shared__ __align__(16) union {
        unsigned short st[2][64 * LROW];      // 2 x 18 KB staging (bf16)
        float red[3][NTRI][64][4];            // 30 KB end-reduce (aliased)
    } sh;

    const int bid = blockIdx.x;
    const int b = bid >> 6;           // / BPB
    const int c = bid & (BPB - 1);

    const int tid  = threadIdx.x;
    const int w    = tid >> 6;        // wave id 0..3 -> K-step within chunk
    const int lane = tid & 63;
    const int m    = lane & 15;
    const int q    = lane >> 4;

    // Staging coords: thread covers rows r0, r0+8, ..., r0+56 at float4 slot kp
    const int r0 = tid >> 5;          // 0..7
    const int kp = tid & 31;          // float4 slot within 128-float chunk row
    const float* gbase = a + (size_t)b * NN * DD + (size_t)c * KC
                           + (size_t)r0 * DD + kp * 4;
    const int lbase = r0 * LROW + kp * 4;   // bf16 units

    const unsigned sel = 0x07060302u;

    floatx4 acc[NTRI];
    #pragma unroll
    for (int i = 0; i < NTRI; ++i) acc[i] = (floatx4)0.0f;

    // Stage chunk cc into buffer buf: 8 coalesced dwordx4 loads per thread
    // (issued back-to-back -> 8 in flight), then cvt+ds_write_b64.
    auto stage = [&](int cc, unsigned short* buf) {
        const float* cb = gbase + cc * CHUNK;
        float4 v[8];
        #pragma unroll
        for (int j = 0; j < 8; ++j)
            v[j] = *(const float4*)(cb + (size_t)(8 * j) * DD);
        #pragma unroll
        for (int j = 0; j < 8; ++j) {
            uint2 h;
            h.x = __builtin_amdgcn_perm(__float_as_uint(v[j].y), __float_as_uint(v[j].x), sel);
            h.y = __builtin_amdgcn_perm(__float_as_uint(v[j].w), __float_as_uint(v[j].z), sel);
            *(uint2*)&buf[lbase + j * 8 * LROW] = h;
        }
    };

    stage(0, sh.st[0]);
    __syncthreads();

    for (int cc = 0; cc < NCHUNK; ++cc) {
        if (cc + 1 < NCHUNK) stage(cc + 1, sh.st[(cc + 1) & 1]);

        // MFMA: wave w handles K-step s=w of this chunk (K=32 slice).
        const unsigned short* buf = sh.st[cc & 1];
        const int fo = w * 32 + q * 8;    // bf16 offset within row
        bf16x8 f0 = *(const bf16x8*)&buf[(m     ) * LROW + fo];
        bf16x8 f1 = *(const bf16x8*)&buf[(m + 16) * LROW + fo];
        bf16x8 f2 = *(const bf16x8*)&buf[(m + 32) * LROW + fo];
        bf16x8 f3 = *(const bf16x8*)&buf[(m + 48) * LROW + fo];
        // acc slots: 0:(0,0) 1:(0,1) 2:(0,2) 3:(0,3) 4:(1,1) 5:(1,2) 6:(1,3)
        //            7:(2,2) 8:(2,3) 9:(3,3); D[4q+r][m] = G[16i+4q+r][16j+m]
        acc[0] = __builtin_amdgcn_mfma_f32_16x16x32_bf16(f0, f0, acc[0], 0, 0, 0);
        acc[1] = __builtin_amdgcn_mfma_f32_16x16x32_bf16(f0, f1, acc[1], 0, 0, 0);
        acc[2] = __builtin_amdgcn_mfma_f32_16x16x32_bf16(f0, f2, acc[2], 0, 0, 0);
        acc[3] = __builtin_amdgcn_mfma_f32_16x16x32_bf16(f0, f3, acc[3], 0, 0, 0);
        acc[4] = __builtin_amdgcn_mfma_f32_16x16x32_bf16(f1, f1, acc[4], 0, 0, 0);
        acc[5] = __builtin_amdgcn_mfma_f32_16x16x32_bf16(f1, f2, acc[5], 0, 0, 0);
        acc[6] = __builtin_amdgcn_mfma_f32_16x16x32_bf16(f1, f3, acc[6], 0, 0, 0);
        acc[7] = __builtin_amdgcn_mfma_f32_16x16x32_bf16(f2, f2, acc[7], 0, 0, 0);
        acc[8] = __builtin_amdgcn_mfma_f32_16x16x32_bf16(f2, f3, acc[8], 0, 0, 0);
        acc[9] = __builtin_amdgcn_mfma_f32_16x16x32_bf16(f3, f3, acc[9], 0, 0, 0);

        __syncthreads();   // protects both dbuf directions (R2-validated)
    }

    // Cross-wave reduce (waves accumulated disjoint K-slices): waves 1..3
    // dump accs into the aliased red buffer (safe: barrier above drained all
    // staging reads); wave 0 sums + stores the tri-partial.
    if (w > 0) {
        #pragma unroll
        for (int t = 0; t < NTRI; ++t)
            *(floatx4*)&sh.red[w - 1][t][lane][0] = acc[t];
    }
    __syncthreads();
    if (w == 0) {
        #pragma unroll
        for (int t = 0; t < NTRI; ++t) {
            floatx4 x0 = *(const floatx4*)&sh.red[0][t][lane][0];
            floatx4 x1 = *(const floatx4*)&sh.red[1][t][lane][0];
            floatx4 x2 = *(const floatx4*)&sh.red[2][t][lane][0];
            acc[t] += (x0 + x1) + x2;
        }
        float* pg = part + (size_t)bid * PSZ;
        #pragma unroll
        for (int t = 0; t < NTRI; ++t) {
            float* tp = pg + t * 256 + m;
            #pragma unroll
            for (int r = 0; r < 4; ++r)
                tp[(q * 4 + r) * 16] = acc[t][r];
        }
    }
}

// ---------------------------------------------------------------------------
// Stage 1b: reduce BPB=64 tri-partials per batch -> gram[8][64*64] row-major.
// Lower triangle reconstructed from the transposed slot (exact: each
// K-partial Gram is symmetric).
// ---------------------------------------------------------------------------
__global__ __launch_bounds__(128) void gram_reduce_kernel(const float* __restrict__ part,
                                                          float* __restrict__ gram) {
    const int gid = blockIdx.x * 128 + threadIdx.x;   // 0 .. 8*4096-1
    const int b   = gid >> 12;
    const int idx = gid & 4095;
    const int i   = idx >> 6;
    const int j   = idx & 63;
    const int ti  = i >> 4, tj = j >> 4;
    const int ib  = ti <= tj ? ti : tj;
    const int jb  = ti <= tj ? tj : ti;
    const int slot = ib * 4 - (ib * (ib - 1)) / 2 + (jb - ib);
    const int rr  = (ti <= tj) ? (i & 15) : (j & 15);
    const int cc  = (ti <= tj) ? (j & 15) : (i & 15);
    const int off = slot * 256 + rr * 16 + cc;
    const float* p = part + (size_t)b * BPB * PSZ + off;

    float s0 = 0.f, s1 = 0.f, s2 = 0.f, s3 = 0.f;
    #pragma unroll 4
    for (int c = 0; c < BPB; c += 4) {
        s0 += p[(size_t)(c + 0) * PSZ];
        s1 += p[(size_t)(c + 1) * PSZ];
        s2 += p[(size_t)(c + 2) * PSZ];
        s3 += p[(size_t)(c + 3) * PSZ];
    }
    gram[gid] = (s0 + s1) + (s2 + s3);
}

// ---------------------------------------------------------------------------
// Stage 2: per-batch CRF iterations. 8 blocks x 256 threads.
// ---------------------------------------------------------------------------
__global__ __launch_bounds__(256) void crf_kernel(const float* __restrict__ gram,
                                                  const float* __restrict__ logits,
                                                  const float* __restrict__ Wm,
                                                  float* __restrict__ out) {
    __shared__ float pp[NN][NN + 1];
    __shared__ float E[NN];
    __shared__ float nrm[NN];
    __shared__ float part[4 * NN];

    const int b  = blockIdx.x;
    const int tid = threadIdx.x;
    const int i  = tid & 63;
    const int jq = tid >> 6;
    const float* g = gram + b * NN * NN;

    if (jq == 0) nrm[i] = sqrtf(g[i * NN + i]);
    E[i] = 0.0f;
    __syncthreads();

    const float ni = nrm[i];
    for (int jj = 0; jj < 16; ++jj) {
        int j = jq * 16 + jj;
        float wsym = 0.5f * (Wm[i * NN + j] + Wm[j * NN + i]);
        pp[i][j] = g[i * NN + j] / (ni * nrm[j] + 1e-6f) * wsym;
    }
    const float li = logits[b * NN + i];
    __syncthreads();

    for (int it = 0; it < 10; ++it) {
        float acc = 0.0f;
        for (int jj = 0; jj < 16; ++jj) {
            int j = jq * 16 + jj;
            float t = li + E[j];
            float s = 1.0f / (1.0f + expf(-t));
            acc = fmaf(2.0f * s - 1.0f, pp[i][j], acc);
        }
        part[jq * NN + i] = acc;
        __syncthreads();
        if (jq == 0)
            E[i] = part[i] + part[NN + i] + part[2 * NN + i] + part[3 * NN + i];
        __syncthreads();
    }

    if (tid < 64) {
        float s = E[tid];
        for (int off = 32; off > 0; off >>= 1) s += __shfl_down(s, off);
        float meanE = __shfl(s, 0) * (1.0f / 64.0f);
        out[b * NN + tid] = logits[b * NN + tid] + meanE;
    }
}

extern "C" void kernel_launch(void* const* d_in, const int* in_sizes, int n_in,
                              void* d_out, int out_size, void* d_ws, size_t ws_size,
                              hipStream_t stream) {
    const float* a      = (const float*)d_in[0];  // [8,64,64,32,32]
    const float* logits = (const float*)d_in[1];  // [8,64]
    const float* Wm     = (const float*)d_in[2];  // [1,64,64]
    float* out  = (float*)d_out;                  // [8,64]

    float* part = (float*)d_ws;                           // [512][2560] fp32
    float* gram = part + (size_t)NBLK * PSZ;              // [8][4096]

    gram_partial_kernel<<<NBLK, 256, 0, stream>>>(a, part);
    gram_reduce_kernel<<<(BATCH * NN * NN) / 128, 128, 0, stream>>>(part, gram);
    crf_kernel<<<BATCH, 256, 0, stream>>>(gram, logits, Wm, out);
}